// Round 2
// baseline (149.661 us; speedup 1.0000x reference)
//
#include <hip/hip_runtime.h>

// Problem constants (match reference): B=32, N=128, Fin=Fout=64, K_HOPS=4
// ws layout (float offsets):
//   Tre  @ 0        : 64*64*128 = 524288   Tre[f][k][m] = T[k][m*64+f]
//   xT   @ 524288   : 32*64*128 = 262144   xT[b][f][n]  = x[b][n][f]
//   PT   @ 786432   : 128*128   = 16384    PT[m][n]     = P[n][m]
//   OQt  @ 802816   : 32*64*128 = 262144   OQt[b][k][n] = (P x + Bb) Q  [b][n][k]
//   Xft  @ 1064960  : 32*64*128 = 262144   Xft[b][f][n] = Xf[b][n][f]
// total 1327104 floats = 5.06 MB of d_ws

#define OFF_TRE 0
#define OFF_XT  524288
#define OFF_PT  786432
#define OFF_OQT 802816
#define OFF_XFT 1064960

__global__ __launch_bounds__(256) void iag_k0_transpose(
    const float* __restrict__ T, const float* __restrict__ x,
    const float* __restrict__ P, float* __restrict__ Tre,
    float* __restrict__ xT, float* __restrict__ PT) {
  int i = blockIdx.x * 256 + threadIdx.x;
  if (i < 524288) {
    // Tre[f][k][m] = T[k][m*64+f]
    int m = i & 127, k = (i >> 7) & 63, f = i >> 13;
    Tre[i] = T[k * 8192 + m * 64 + f];
  } else if (i < 786432) {
    // xT[b][f][n] = x[b][n][f]
    int j = i - 524288;
    int n = j & 127, f = (j >> 7) & 63, b = j >> 13;
    xT[j] = x[b * 8192 + n * 64 + f];
  } else {
    // PT[m][n] = P[n][m]
    int p = i - 786432;
    int n = p & 127, m = p >> 7;
    PT[p] = P[n * 128 + m];
  }
}

// k1: per (b, row-chunk of 32): O = P x + Bb (chunk), then OQt[b][k][n] = (O Q)^T
__global__ __launch_bounds__(256) void iag_k1_oq(
    const float* __restrict__ x, const float* __restrict__ PT,
    const float* __restrict__ Q, const float* __restrict__ Bb,
    float* __restrict__ OQt) {
  __shared__ __align__(16) float x_s[128 * 64];   // [m][k]
  __shared__ __align__(16) float Pr[128 * 32];    // [m][nl] = P[r0+nl][m]
  __shared__ __align__(16) float Q_s[64 * 64];    // [k][j]
  __shared__ __align__(16) float OcT[64 * 32];    // [k][nl]
  int b = blockIdx.y, r0 = blockIdx.x * 32;
  int tid = threadIdx.x;

  const float4* xg = (const float4*)(x + b * 8192);
  float4* xs4 = (float4*)x_s;
  for (int idx = tid; idx < 2048; idx += 256) xs4[idx] = xg[idx];
  const float4* pg = (const float4*)PT;
  float4* ps4 = (float4*)Pr;
  for (int idx = tid; idx < 1024; idx += 256) {
    int m = idx >> 3, i4 = idx & 7;
    ps4[idx] = pg[m * 32 + (r0 >> 2) + i4];
  }
  const float4* qg = (const float4*)Q;
  float4* qs4 = (float4*)Q_s;
  for (int idx = tid; idx < 1024; idx += 256) qs4[idx] = qg[idx];
  __syncthreads();

  {  // Stage A: O[nl][k0..k0+7]
    int nl = tid & 31, k0 = (tid >> 5) * 8;
    float bias = Bb[r0 + nl];
    float a[8];
#pragma unroll
    for (int j = 0; j < 8; ++j) a[j] = bias;
#pragma unroll 4
    for (int m = 0; m < 128; ++m) {
      float p = Pr[m * 32 + nl];
      float4 x0 = xs4[m * 16 + (k0 >> 2)];
      float4 x1 = xs4[m * 16 + (k0 >> 2) + 1];
      a[0] += p * x0.x; a[1] += p * x0.y; a[2] += p * x0.z; a[3] += p * x0.w;
      a[4] += p * x1.x; a[5] += p * x1.y; a[6] += p * x1.z; a[7] += p * x1.w;
    }
#pragma unroll
    for (int j = 0; j < 8; ++j) OcT[(k0 + j) * 32 + nl] = a[j];
  }
  __syncthreads();
  {  // Stage B: OQt[b][j][r0+nl0 .. +7]
    int j = tid >> 2, nl0 = (tid & 3) * 8;
    float c[8];
#pragma unroll
    for (int i = 0; i < 8; ++i) c[i] = 0.f;
    const float4* oc4 = (const float4*)OcT;
#pragma unroll 4
    for (int k = 0; k < 64; ++k) {
      float q = Q_s[k * 64 + j];
      float4 o0 = oc4[k * 8 + (nl0 >> 2)];
      float4 o1 = oc4[k * 8 + (nl0 >> 2) + 1];
      c[0] += q * o0.x; c[1] += q * o0.y; c[2] += q * o0.z; c[3] += q * o0.w;
      c[4] += q * o1.x; c[5] += q * o1.y; c[6] += q * o1.z; c[7] += q * o1.w;
    }
    float4* og = (float4*)(OQt + b * 8192 + j * 128 + r0 + nl0);
    og[0] = make_float4(c[0], c[1], c[2], c[3]);
    og[1] = make_float4(c[4], c[5], c[6], c[7]);
  }
}

// k2: per (f, b): G-tile in registers, relu, degree-normalize, 3 matvec hops.
__global__ __launch_bounds__(256) void iag_k2_graph(
    const float* __restrict__ OQt_g, const float* __restrict__ Tre,
    const float* __restrict__ xT, float* __restrict__ Xft) {
  __shared__ __align__(16) float OQ_s[64 * 128];  // [k][n]
  __shared__ __align__(16) float Tf_s[64 * 128];  // [k][m]
  __shared__ __align__(16) float red[16 * 128];
  __shared__ float inv_c[128], inv_r[128];
  __shared__ __align__(16) float wv[128];
  __shared__ float sv[128];
  int f = blockIdx.x, b = blockIdx.y, tid = threadIdx.x;

  const float4* og = (const float4*)(OQt_g + b * 8192);
  float4* os = (float4*)OQ_s;
  for (int idx = tid; idx < 2048; idx += 256) os[idx] = og[idx];
  const float4* tg = (const float4*)(Tre + f * 8192);
  float4* ts = (float4*)Tf_s;
  for (int idx = tid; idx < 2048; idx += 256) ts[idx] = tg[idx];
  if (tid < 128) {
    float v = xT[(b * 64 + f) * 128 + tid];
    wv[tid] = v; sv[tid] = v;
  }
  __syncthreads();

  int tx = tid & 15, ty = tid >> 4;
  int n0 = ty * 8, m0 = tx * 8;

  float acc[8][8];
#pragma unroll
  for (int i = 0; i < 8; ++i)
#pragma unroll
    for (int j = 0; j < 8; ++j) acc[i][j] = 0.f;

  const float4* o4 = (const float4*)OQ_s;
  const float4* t4 = (const float4*)Tf_s;
#pragma unroll 4
  for (int k = 0; k < 64; ++k) {
    float4 a0 = o4[k * 32 + (n0 >> 2)];
    float4 a1 = o4[k * 32 + (n0 >> 2) + 1];
    float4 b0 = t4[k * 32 + (m0 >> 2)];
    float4 b1 = t4[k * 32 + (m0 >> 2) + 1];
    float av[8] = {a0.x, a0.y, a0.z, a0.w, a1.x, a1.y, a1.z, a1.w};
    float bv[8] = {b0.x, b0.y, b0.z, b0.w, b1.x, b1.y, b1.z, b1.w};
#pragma unroll
    for (int i = 0; i < 8; ++i)
#pragma unroll
      for (int j = 0; j < 8; ++j) acc[i][j] += av[i] * bv[j];
  }
  // relu
#pragma unroll
  for (int i = 0; i < 8; ++i)
#pragma unroll
    for (int j = 0; j < 8; ++j) acc[i][j] = fmaxf(acc[i][j], 0.f);

  // column sums (index m0+j) and row sums (index n0+i)
  {
    float pc[8];
#pragma unroll
    for (int j = 0; j < 8; ++j) {
      pc[j] = 0.f;
#pragma unroll
      for (int i = 0; i < 8; ++i) pc[j] += acc[i][j];
    }
#pragma unroll
    for (int j = 0; j < 8; ++j) red[ty * 128 + m0 + j] = pc[j];
  }
  __syncthreads();
  if (tid < 128) {
    float c = 0.f;
#pragma unroll
    for (int t = 0; t < 16; ++t) c += red[t * 128 + tid];
    inv_c[tid] = 1.0f / sqrtf(c);
  }
  __syncthreads();
  {
    float pr[8];
#pragma unroll
    for (int i = 0; i < 8; ++i) {
      pr[i] = 0.f;
#pragma unroll
      for (int j = 0; j < 8; ++j) pr[i] += acc[i][j];
    }
#pragma unroll
    for (int i = 0; i < 8; ++i) red[tx * 128 + n0 + i] = pr[i];
  }
  __syncthreads();
  if (tid < 128) {
    float r = 0.f;
#pragma unroll
    for (int t = 0; t < 16; ++t) r += red[t * 128 + tid];
    inv_r[tid] = 1.0f / sqrtf(r);
  }
  __syncthreads();

  // normalize in-register: A[n][m] = G * inv_c[n] * inv_r[m]
  {
    float ic[8], ir[8];
#pragma unroll
    for (int i = 0; i < 8; ++i) ic[i] = inv_c[n0 + i];
#pragma unroll
    for (int j = 0; j < 8; ++j) ir[j] = inv_r[m0 + j];
#pragma unroll
    for (int i = 0; i < 8; ++i)
#pragma unroll
      for (int j = 0; j < 8; ++j) acc[i][j] *= ic[i] * ir[j];
  }

  // 3 hops: w' = A w; s += w'
  for (int h = 0; h < 3; ++h) {
    float4 w0 = ((const float4*)wv)[m0 >> 2];
    float4 w1 = ((const float4*)wv)[(m0 >> 2) + 1];
    float w[8] = {w0.x, w0.y, w0.z, w0.w, w1.x, w1.y, w1.z, w1.w};
    float p[8];
#pragma unroll
    for (int i = 0; i < 8; ++i) {
      float s = 0.f;
#pragma unroll
      for (int j = 0; j < 8; ++j) s += acc[i][j] * w[j];
      p[i] = s;
    }
#pragma unroll
    for (int i = 0; i < 8; ++i) red[tx * 128 + n0 + i] = p[i];
    __syncthreads();
    if (tid < 128) {
      float s = 0.f;
#pragma unroll
      for (int t = 0; t < 16; ++t) s += red[t * 128 + tid];
      sv[tid] += s;
      wv[tid] = s;
    }
    __syncthreads();
  }

  if (tid < 128) Xft[(b * 64 + f) * 128 + tid] = sv[tid];
}

// k3: out[b][n][j] = sum_f Xft[b][f][n] * U[f][j]
__global__ __launch_bounds__(256) void iag_k3_out(
    const float* __restrict__ Xft, const float* __restrict__ U,
    float* __restrict__ out) {
  __shared__ __align__(16) float Xf_s[64 * 128];
  __shared__ __align__(16) float U_s[64 * 64];
  int b = blockIdx.x, tid = threadIdx.x;
  const float4* xg = (const float4*)(Xft + b * 8192);
  float4* xs = (float4*)Xf_s;
  for (int idx = tid; idx < 2048; idx += 256) xs[idx] = xg[idx];
  const float4* ug = (const float4*)U;
  float4* us = (float4*)U_s;
  for (int idx = tid; idx < 1024; idx += 256) us[idx] = ug[idx];
  __syncthreads();

  int n0 = (tid & 15) * 8, j0 = (tid >> 4) * 4;
  float acc[8][4];
#pragma unroll
  for (int i = 0; i < 8; ++i)
#pragma unroll
    for (int j = 0; j < 4; ++j) acc[i][j] = 0.f;

  const float4* x4 = (const float4*)Xf_s;
  const float4* u4 = (const float4*)U_s;
#pragma unroll 4
  for (int f = 0; f < 64; ++f) {
    float4 xa = x4[f * 32 + (n0 >> 2)];
    float4 xb = x4[f * 32 + (n0 >> 2) + 1];
    float4 u = u4[f * 16 + (j0 >> 2)];
    float xv[8] = {xa.x, xa.y, xa.z, xa.w, xb.x, xb.y, xb.z, xb.w};
    float uv[4] = {u.x, u.y, u.z, u.w};
#pragma unroll
    for (int i = 0; i < 8; ++i)
#pragma unroll
      for (int j = 0; j < 4; ++j) acc[i][j] += xv[i] * uv[j];
  }
#pragma unroll
  for (int i = 0; i < 8; ++i) {
    float4* og = (float4*)(out + b * 8192 + (n0 + i) * 64 + j0);
    og[0] = make_float4(acc[i][0], acc[i][1], acc[i][2], acc[i][3]);
  }
}

extern "C" void kernel_launch(void* const* d_in, const int* in_sizes, int n_in,
                              void* d_out, int out_size, void* d_ws, size_t ws_size,
                              hipStream_t stream) {
  const float* x  = (const float*)d_in[0];
  const float* P  = (const float*)d_in[1];
  const float* Bb = (const float*)d_in[2];
  const float* Q  = (const float*)d_in[3];
  const float* T  = (const float*)d_in[4];
  const float* U  = (const float*)d_in[5];
  float* ws = (float*)d_ws;
  float* Tre = ws + OFF_TRE;
  float* xT  = ws + OFF_XT;
  float* PT  = ws + OFF_PT;
  float* OQt = ws + OFF_OQT;
  float* Xft = ws + OFF_XFT;

  iag_k0_transpose<<<3136, 256, 0, stream>>>(T, x, P, Tre, xT, PT);
  iag_k1_oq<<<dim3(4, 32), 256, 0, stream>>>(x, PT, Q, Bb, OQt);
  iag_k2_graph<<<dim3(64, 32), 256, 0, stream>>>(OQt, Tre, xT, Xft);
  iag_k3_out<<<32, 256, 0, stream>>>(Xft, U, (float*)d_out);
}